// Round 11
// baseline (166.039 us; speedup 1.0000x reference)
//
#include <hip/hip_runtime.h>
#include <stdint.h>

// Problem constants
#define ROWS  16384   // B*T = 512*32
#define CELL  128
#define INF   512
#define RPB   16      // rows per block
#define NSTEP 32

typedef _Float16 f16x8 __attribute__((ext_vector_type(8)));
typedef _Float16 f16x4 __attribute__((ext_vector_type(4)));
typedef float    f32x4 __attribute__((ext_vector_type(4)));

#define MFMA16(a, b, c) __builtin_amdgcn_mfma_f32_16x16x32_f16((a), (b), (c), 0, 0, 0)

// ws layout (f16 elems), all in 16x16x32 fragment order:
//   A_sw[g]  at g*16384          (g=0..3: Wf,Wi1,Wi2,Wo rows 0..127, cell part)
//   Xw_sw[g] at 65536 + g*65536  (rows 128..639, x part)
//   Wc_sw    at 327680
// frag addr: ((ks*8 + nb)*64 + lane)*8 + j  <->
//   W[ks*32 + ((lane>>4)<<3) + j][nb*16 + (lane&15)]
// Weights PRE-SCALED: Wf,Wi1,Wo by log2(e); Wi2 by 2*log2(e); Wc by log2(e).
#define AOFF  0
#define XOFF  65536
#define WCOFF 327680
#define WSTOT 344064
#define NT8   (WSTOT / 8)   // 43008 threads, one f16x8 store each

#define LOG2E  1.44269504f
#define LOG2E2 2.88539008f

__device__ __forceinline__ float sig2(float z) {
  return __builtin_amdgcn_rcpf(1.f + __builtin_amdgcn_exp2f(-z));
}
__device__ __forceinline__ float tanh2(float z) {
  return 1.f - 2.f * __builtin_amdgcn_rcpf(__builtin_amdgcn_exp2f(z) + 1.f);
}

// prep v2: COALESCED (verified R9). Thread t emits ws[t*8..t*8+7].
__global__ __launch_bounds__(256) void prep_kernel(
    const float* __restrict__ Wf, const float* __restrict__ Wi1,
    const float* __restrict__ Wi2, const float* __restrict__ Wo,
    const float* __restrict__ Wc, unsigned short* __restrict__ ws) {
  int t = blockIdx.x * blockDim.x + threadIdx.x;
  if (t >= NT8) return;
  const float* Wg[4] = {Wf, Wi1, Wi2, Wo};
  const float scl[4] = {LOG2E, LOG2E, LOG2E2, LOG2E};
  const int lane = t & 63;
  const int tile = t >> 6;             // global 512-f16 tile, 0..671

  const float* src;
  float sc;
  int ks, nb;
  if (tile < 128) {                    // A region: recurrent (cell) part
    int g = tile >> 5, tA = tile & 31;
    ks = tA >> 3; nb = tA & 7;
    sc = scl[g];
    src = Wg[g];
  } else if (tile < 640) {             // X region: x part, W rows 128..639
    int rel = tile - 128;
    int g = rel >> 7, tX = rel & 127;
    ks = tX >> 3; nb = tX & 7;
    sc = scl[g];
    src = Wg[g] + 128 * CELL;
  } else {                             // Wc region
    int rel = tile - 640;
    ks = rel >> 3; nb = rel & 7;
    sc = LOG2E;
    src = Wc;
  }
  const int k0 = ks * 32 + ((lane >> 4) << 3);
  const int n  = nb * 16 + (lane & 15);
  const float* p = src + (size_t)k0 * CELL + n;
  f16x8 hv;
#pragma unroll
  for (int j = 0; j < 8; ++j) hv[j] = (_Float16)(p[j * CELL] * sc);
  *(f16x8*)&ws[(size_t)t * 8] = hv;
}

// R9 structure (best measured lstm: 87.8-89.4 us) + R10's fused gate math
// (verified correct): cn = cr*sig(zf) + sig(zi1)*tanh(zi2) with one shared
// rcp — 5 trans/element instead of 6. fminf(zi2,126) guards E=inf.
__global__ __launch_bounds__(512, 4) void lstm_kernel(
    const float* __restrict__ x,
    const float* __restrict__ bf_, const float* __restrict__ bi1,
    const float* __restrict__ bi2, const float* __restrict__ bo,
    const float* __restrict__ bc,
    const unsigned short* __restrict__ ws, float* __restrict__ out) {

  __shared__ _Float16 cF[2][16 * 128];       // 8192 B, double-buffered c (swz)
  __shared__ union {
    _Float16 xs[16 * 512];                   // 16384 B, x staging (swz)
    struct {
      float    e[16][132];                   // 8448 B, softmax exp values
      _Float16 o[16 * 128];                  // 4096 B, o activations (swz)
    } ep;                                    // 12544 B
  } uS;                                      // total LDS: 24576 B

  const int tid  = threadIdx.x;
  const int lane = tid & 63;
  const int w    = tid >> 6;     // wave 0..7
  const int n16  = lane & 15;    // this lane's batch row (output mapping)
  const int g4   = lane >> 4;    // 0..3
  const int sxor = n16 & 7;      // per-row swizzle key
  const int col0 = w * 16 + g4 * 4;  // first of this lane's 4 output columns
  const int r0   = blockIdx.x * RPB;

  const _Float16* Aw  = (const _Float16*)ws + AOFF;
  const _Float16* Xw  = (const _Float16*)ws + XOFF;
  const _Float16* Wcw = (const _Float16*)ws + WCOFF;

  // loop-invariant swizzled fragment offsets (f16 units) for cF / ep.o
  int aoff[4];
#pragma unroll
  for (int ks = 0; ks < 4; ++ks)
    aoff[ks] = n16 * 128 + (((4 * ks + g4) ^ sxor) << 3);
  const int woff = n16 * 128 + (((2 * w + (g4 >> 1)) ^ sxor) << 3) + (g4 & 1) * 4;

  // ---------------- stage x (16 rows x 512 f32 -> f16, swizzled) ----------
  {
    const float* xb = x + (size_t)r0 * INF;
#pragma unroll
    for (int i = 0; i < 4; ++i) {
      int flat = tid + i * 512;            // 2048 = 16 rows * 128 float4
      int row = flat >> 7, c4 = flat & 127;
      const float4 v = ((const float4*)(xb + (size_t)row * INF))[c4];
      f16x4 h = {(_Float16)v.x, (_Float16)v.y, (_Float16)v.z, (_Float16)v.w};
      int idx = row * 512 + (((c4 >> 1) ^ (row & 7)) << 3) + (c4 & 1) * 4;
      *(f16x4*)&uS.xs[idx] = h;
    }
  }
  __syncthreads();

  // ---------------- u_g = x @ Wg[128:,:] + b ------------------------------
  f32x4 u[4];
#pragma unroll
  for (int g = 0; g < 4; ++g)
#pragma unroll
    for (int i = 0; i < 4; ++i) u[g][i] = 0.f;

#pragma unroll 4
  for (int ks = 0; ks < 16; ++ks) {
    f16x8 a = *(const f16x8*)&uS.xs[n16 * 512 + (((4 * ks + g4) ^ sxor) << 3)];
#pragma unroll
    for (int g = 0; g < 4; ++g) {
      f16x8 b = *(const f16x8*)(Xw + g * 65536 + ((ks * 8 + w) * 64 + lane) * 8);
      u[g] = MFMA16(b, a, u[g]);
    }
  }
  {
    f32x4 b0 = *(const f32x4*)&bf_[col0];
    f32x4 b1 = *(const f32x4*)&bi1[col0];
    f32x4 b2 = *(const f32x4*)&bi2[col0];
    f32x4 b3 = *(const f32x4*)&bo[col0];
#pragma unroll
    for (int i = 0; i < 4; ++i) {
      u[0][i] = fmaf(b0[i], LOG2E,  u[0][i]);
      u[1][i] = fmaf(b1[i], LOG2E,  u[1][i]);
      u[2][i] = fmaf(b2[i], LOG2E2, u[2][i]);
      u[3][i] = fmaf(b3[i], LOG2E,  u[3][i]);
    }
  }

  // ---------------- recurrent-gate weights -> registers -------------------
  f16x8 wr[3][4];   // [gate f,i1,i2][ks] -> 48 VGPRs
#pragma unroll
  for (int g = 0; g < 3; ++g)
#pragma unroll
    for (int ks = 0; ks < 4; ++ks)
      wr[g][ks] = *(const f16x8*)(Aw + g * 16384 + ((ks * 8 + w) * 64 + lane) * 8);

  // fused cell update: cn = cr*sig(zf) + sig(zi1)*tanh(zi2), 5 trans/elem
#define GATES(ZF, ZI, ZG, CR, BUF) { \
  f16x4 hv; \
  _Pragma("unroll") \
  for (int i = 0; i < 4; ++i) { \
    float F = __builtin_amdgcn_exp2f(-(ZF)[i]); \
    float A = __builtin_amdgcn_exp2f(-(ZI)[i]); \
    float E = __builtin_amdgcn_exp2f(fminf((ZG)[i], 126.f)); \
    float fg  = __builtin_amdgcn_rcpf(1.f + F); \
    float igg = (E - 1.f) * __builtin_amdgcn_rcpf((1.f + A) * (E + 1.f)); \
    float cn = fmaf((CR)[i], fg, igg); \
    (CR)[i] = cn; \
    hv[i] = (_Float16)cn; \
  } \
  *(f16x4*)&(BUF)[woff] = hv; }

  // ---------------- step 0: c_prev = 0 => cn = sig*tanh -------------------
  f32x4 cr;
#pragma unroll
  for (int i = 0; i < 4; ++i) cr[i] = 0.f;
  GATES(u[0], u[1], u[2], cr, cF[0])
  __syncthreads();

  // ---------------- recurrence: steps 1..30 -------------------------------
#pragma unroll 1
  for (int t = 1; t < NSTEP - 1; ++t) {
    const _Float16* rd = cF[(t + 1) & 1];
    f16x8 a0 = *(const f16x8*)(rd + aoff[0]);
    f16x8 a1 = *(const f16x8*)(rd + aoff[1]);
    f16x8 a2 = *(const f16x8*)(rd + aoff[2]);
    f16x8 a3 = *(const f16x8*)(rd + aoff[3]);
    // seed accumulators from u via the MFMA C operand (no reg copies)
    f32x4 zf  = MFMA16(wr[0][0], a0, u[0]);
    f32x4 zi1 = MFMA16(wr[1][0], a0, u[1]);
    f32x4 zi2 = MFMA16(wr[2][0], a0, u[2]);
    zf  = MFMA16(wr[0][1], a1, zf);
    zi1 = MFMA16(wr[1][1], a1, zi1);
    zi2 = MFMA16(wr[2][1], a1, zi2);
    zf  = MFMA16(wr[0][2], a2, zf);
    zi1 = MFMA16(wr[1][2], a2, zi1);
    zi2 = MFMA16(wr[2][2], a2, zi2);
    zf  = MFMA16(wr[0][3], a3, zf);
    zi1 = MFMA16(wr[1][3], a3, zi1);
    zi2 = MFMA16(wr[2][3], a3, zi2);
    _Float16* wp = cF[t & 1];
    GATES(zf, zi1, zi2, cr, wp)
    __syncthreads();
  }

  // ---------------- final step (t=31): + o-gate ---------------------------
  {
    const _Float16* rd = cF[0];            // written at t=30
    f16x8 a0 = *(const f16x8*)(rd + aoff[0]);
    f16x8 a1 = *(const f16x8*)(rd + aoff[1]);
    f16x8 a2 = *(const f16x8*)(rd + aoff[2]);
    f16x8 a3 = *(const f16x8*)(rd + aoff[3]);
    f16x8 bo0 = *(const f16x8*)(Aw + 3 * 16384 + ((0 * 8 + w) * 64 + lane) * 8);
    f16x8 bo1 = *(const f16x8*)(Aw + 3 * 16384 + ((1 * 8 + w) * 64 + lane) * 8);
    f16x8 bo2 = *(const f16x8*)(Aw + 3 * 16384 + ((2 * 8 + w) * 64 + lane) * 8);
    f16x8 bo3 = *(const f16x8*)(Aw + 3 * 16384 + ((3 * 8 + w) * 64 + lane) * 8);
    f32x4 zf  = MFMA16(wr[0][0], a0, u[0]);
    f32x4 zi1 = MFMA16(wr[1][0], a0, u[1]);
    f32x4 zi2 = MFMA16(wr[2][0], a0, u[2]);
    f32x4 zo  = MFMA16(bo0,      a0, u[3]);
    zf  = MFMA16(wr[0][1], a1, zf);
    zi1 = MFMA16(wr[1][1], a1, zi1);
    zi2 = MFMA16(wr[2][1], a1, zi2);
    zo  = MFMA16(bo1,      a1, zo);
    zf  = MFMA16(wr[0][2], a2, zf);
    zi1 = MFMA16(wr[1][2], a2, zi1);
    zi2 = MFMA16(wr[2][2], a2, zi2);
    zo  = MFMA16(bo2,      a2, zo);
    zf  = MFMA16(wr[0][3], a3, zf);
    zi1 = MFMA16(wr[1][3], a3, zi1);
    zi2 = MFMA16(wr[2][3], a3, zi2);
    zo  = MFMA16(bo3,      a3, zo);
    f16x4 hv;
#pragma unroll
    for (int i = 0; i < 4; ++i) {
      float F = __builtin_amdgcn_exp2f(-zf[i]);
      float A = __builtin_amdgcn_exp2f(-zi1[i]);
      float E = __builtin_amdgcn_exp2f(fminf(zi2[i], 126.f));
      float fg  = __builtin_amdgcn_rcpf(1.f + F);
      float igg = (E - 1.f) * __builtin_amdgcn_rcpf((1.f + A) * (E + 1.f));
      float cn = fmaf(cr[i], fg, igg);
      cr[i] = cn;
      float ov = sig2(zo[i]) * tanh2(cn * LOG2E2);  // cn unscaled
      hv[i] = (_Float16)ov;
    }
    // xs region is long dead; o is disjoint from cF
    *(f16x4*)&uS.ep.o[woff] = hv;
    __syncthreads();
  }

  // -------- epilogue: e = exp2(o @ Wc_scaled + bc*log2e), softmax ---------
  // |s| small (o in (-1,1), Wc ~ N(0,1/sqrt(128))) => max-free softmax.
  {
    f32x4 sacc;
#pragma unroll
    for (int i = 0; i < 4; ++i) sacc[i] = 0.f;
#pragma unroll
    for (int ks = 0; ks < 4; ++ks) {
      f16x8 a = *(const f16x8*)&uS.ep.o[aoff[ks]];
      f16x8 b = *(const f16x8*)(Wcw + ((ks * 8 + w) * 64 + lane) * 8);
      sacc = MFMA16(b, a, sacc);
    }
    f32x4 bcv = *(const f32x4*)&bc[col0];
    f32x4 ev;
#pragma unroll
    for (int i = 0; i < 4; ++i)
      ev[i] = __builtin_amdgcn_exp2f(fmaf(bcv[i], LOG2E, sacc[i]));
    *(f32x4*)&uS.ep.e[n16][col0] = ev;     // single b128 store (e is padded f32)
    __syncthreads();

    // wave w reduces rows w*2, w*2+1; lane covers cols {lane, lane+64}
#pragma unroll
    for (int rr = 0; rr < 2; ++rr) {
      int r = w * 2 + rr;
      float e0 = uS.ep.e[r][lane];
      float e1 = uS.ep.e[r][lane + 64];
      float sm = e0 + e1;
#pragma unroll
      for (int off = 32; off; off >>= 1) sm += __shfl_xor(sm, off, 64);
      float inv = __builtin_amdgcn_rcpf(sm);
      size_t base = (size_t)(r0 + r) * 128;
      out[base + lane]      = e0 * inv;
      out[base + lane + 64] = e1 * inv;
    }

    // final c (output 1) at offset ROWS*128 — float4 store per lane
    *(f32x4*)&out[(size_t)ROWS * 128 + (size_t)(r0 + n16) * 128 + col0] = cr;
  }
}

extern "C" void kernel_launch(void* const* d_in, const int* in_sizes, int n_in,
                              void* d_out, int out_size, void* d_ws, size_t ws_size,
                              hipStream_t stream) {
  const float* x   = (const float*)d_in[0];
  const float* Wf  = (const float*)d_in[1];
  const float* bf_ = (const float*)d_in[2];
  const float* Wi1 = (const float*)d_in[3];
  const float* bi1 = (const float*)d_in[4];
  const float* Wi2 = (const float*)d_in[5];
  const float* bi2 = (const float*)d_in[6];
  const float* Wo  = (const float*)d_in[7];
  const float* bo  = (const float*)d_in[8];
  const float* Wc  = (const float*)d_in[9];
  const float* bc  = (const float*)d_in[10];
  unsigned short* ws = (unsigned short*)d_ws;
  float* out = (float*)d_out;

  hipLaunchKernelGGL(prep_kernel, dim3((NT8 + 255) / 256), dim3(256), 0, stream,
                     Wf, Wi1, Wi2, Wo, Wc, ws);
  hipLaunchKernelGGL(lstm_kernel, dim3(ROWS / RPB), dim3(512), 0, stream,
                     x, bf_, bi1, bi2, bo, bc, ws, out);
}